// Round 4
// baseline (307.570 us; speedup 1.0000x reference)
//
#include <hip/hip_runtime.h>
#include <cstddef>

#define BATCH 4
#define CH    16
#define HH    512
#define WW    512
#define HID   128
#define K3    48
#define XW    28      // floats per (ch, slot): 24 data [j0-4, j0+20) + 4 pad (banks)
#define YSTR  72      // sY row stride bf16 (48 feats + 16 K-pad + 8 bank-pad)
#define HSTR  136     // sH row stride bf16 (128 + 8 bank-pad)
#define ROWS  8       // output rows per wave-tile
#define TPX   16      // pixels per wave-tile (one MFMA n-tile)

typedef __bf16 bf16x8 __attribute__((ext_vector_type(8)));
typedef __bf16 bf16x4 __attribute__((ext_vector_type(4)));
typedef float  f32x4  __attribute__((ext_vector_type(4)));

static __device__ __forceinline__ f32x4 mfma16(bf16x8 a, bf16x8 b, f32x4 c) {
    return __builtin_amdgcn_mfma_f32_16x16x32_bf16(a, b, c, 0, 0, 0);
}

// Wave-independent design: each wave owns a 16px x 8row tile; NO barriers in
// the main loop. x rows staged via async global_load_lds into a wave-private
// 3-slot rolling buffer (zero VGPR cost -> compiler cannot sink the prefetch;
// explicit s_waitcnt vmcnt(4) keeps exactly the next batch in flight).
// Weights live in registers (round-2-validated fragment math, bias folded in
// as feature k==48 = 1.0). Residual add uses exact fp32 x from the buffer.
__global__ __launch_bounds__(256, 3)
void ca_wave(const float* __restrict__ x, const float* __restrict__ w0,
             const float* __restrict__ b0, const float* __restrict__ w1,
             const float* __restrict__ ru, float* __restrict__ out)
{
    __shared__ __align__(16) float  sX[4][3][CH][XW];   // 21.0 KB [wave][slot][ch][px]
    __shared__ __align__(16) __bf16 sY[4][TPX][YSTR];   //  9.0 KB
    __shared__ __align__(16) __bf16 sH[4][TPX][HSTR];   // 17.0 KB  (total 47 KB -> 3 blk/CU)

    const int tid  = threadIdx.x;
    const int lane = tid & 63;
    const int wv   = tid >> 6;
    const int p    = lane & 15;   // MFMA m (A) / n (B,D) index
    const int q    = lane >> 4;   // quad

    const int wid = blockIdx.x * 4 + wv;   // 0..8191 wave-tiles
    const int b   = wid >> 11;             // batch
    const int rem = wid & 2047;            // 64 i-tiles * 32 j-tiles
    const int i0  = (rem >> 5) * ROWS;
    const int j0  = (rem & 31) * TPX;

    const size_t plane = (size_t)HH * WW;
    const float* xb = x + (size_t)b * CH * plane;

    // ---- weights -> registers (A-fragments; bias carried at k==48) ----
    bf16x8 a0[8], a1[8], aw1[4];
    #pragma unroll
    for (int t = 0; t < 8; ++t) {
        const int o = 16 * t + p;
        #pragma unroll
        for (int j = 0; j < 8; ++j) {
            const int k0 = 8 * q + j;
            a0[t][j] = (__bf16)w0[o * K3 + k0];
            const int k1 = 32 + 8 * q + j;
            float v;
            if (k1 < K3)       v = w0[o * K3 + k1];
            else if (k1 == K3) v = b0[o];
            else               v = 0.f;
            a1[t][j] = (__bf16)v;
        }
    }
    #pragma unroll
    for (int s = 0; s < 4; ++s)
        #pragma unroll
        for (int j = 0; j < 8; ++j)
            aw1[s][j] = (__bf16)w1[p * HID + 32 * s + 8 * q + j];

    // ---- static K-pad of sY rows: feature 48 = 1.0 (bias), 49..63 = 0 ----
    if (lane < TPX) {
        bf16x8 z0, z1;
        #pragma unroll
        for (int j = 0; j < 8; ++j) { z0[j] = (__bf16)0.f; z1[j] = (__bf16)0.f; }
        z0[0] = (__bf16)1.0f;
        *(bf16x8*)&sY[wv][lane][48] = z0;
        *(bf16x8*)&sY[wv][lane][56] = z1;
    }

    const int lo = (j0 == 0) ? 1 : 0;          // skip lane 0 (j<0) at left edge
    const int hi = (j0 == WW - TPX) ? 5 : 6;   // skip lane 5 (j>=512) at right edge

    // async-stage input row ri into slot sl (wave-private). Slice float f <-> j0-4+f.
    auto prefetch_row = [&](int ri, int sl) {
        float* sbase = &sX[wv][sl][0][0];
        if (ri < 0 || ri >= HH) {              // OOB row: zero the slice
            f32x4 z{0.f, 0.f, 0.f, 0.f};
            #pragma unroll
            for (int e = 0; e < 2; ++e) {
                const int idx = lane + 64 * e;
                if (idx < CH * XW / 4) *(f32x4*)(sbase + idx * 4) = z;
            }
            return;
        }
        const float* src = xb + (size_t)ri * WW + (j0 - 4);
        if (lane >= lo && lane < hi) {
            #pragma unroll
            for (int c = 0; c < CH; ++c) {
                __builtin_amdgcn_global_load_lds(
                    (const __attribute__((address_space(1))) void*)(src + (size_t)c * plane + lane * 4),
                    (__attribute__((address_space(3))) void*)&sX[wv][sl][c][0],
                    16, 0, 0);
            }
        }
        if (j0 == 0        && lane < CH) sX[wv][sl][lane][3]  = 0.f;  // j=-1 -> 0
        if (j0 == WW - TPX && lane < CH) sX[wv][sl][lane][20] = 0.f;  // j=512 -> 0
    };

    // prologue: slots for rows i0-1, i0, i0+1 ; ru for row i0
    prefetch_row(i0 - 1, 0);
    prefetch_row(i0,     1);
    prefetch_row(i0 + 1, 2);
    float ru_c = ru[(size_t)b * plane + (size_t)i0 * WW + j0 + p];
    float ru_n = 0.f;

    for (int r = 0; r < ROWS; ++r) {
        // wait: row r+1 slice (and ru) complete; allow newest 4 (stores) in flight
        if (r == 0) __builtin_amdgcn_s_waitcnt(0x0F70);   // vmcnt(0)
        else        __builtin_amdgcn_s_waitcnt(0x0F74);   // vmcnt(4)

        const int sm1 = r % 3, s0 = (r + 1) % 3, sp1 = (r + 2) % 3;

        // ---- Sobel features: lane (p,q) does px=p, ch 4q..4q+3 ----
        const int c0 = 4 * q;
        const int ix = p + 4;
        float xmv[4], gxv[4], gyv[4];
        #pragma unroll
        for (int k = 0; k < 4; ++k) {
            const int c = c0 + k;
            const float* Sm = &sX[wv][sm1][c][0];
            const float* S0 = &sX[wv][s0][c][0];
            const float* Sp = &sX[wv][sp1][c][0];
            const float xul = Sm[ix - 1], xu = Sm[ix], xur = Sm[ix + 1];
            const float xl  = S0[ix - 1], xm = S0[ix], xr  = S0[ix + 1];
            const float xdl = Sp[ix - 1], xd = Sp[ix], xdr = Sp[ix + 1];
            xmv[k] = xm;
            gxv[k] = (xur - xul) + 2.f * (xr - xl) + (xdr - xdl);
            gyv[k] = (xdl - xul) + 2.f * (xd - xu) + (xdr - xur);
        }
        bf16x4 vm_, vx_, vy_;
        #pragma unroll
        for (int k = 0; k < 4; ++k) {
            vm_[k] = (__bf16)xmv[k];
            vx_[k] = (__bf16)gxv[k];
            vy_[k] = (__bf16)gyv[k];
        }
        *(bf16x4*)&sY[wv][p][c0]      = vm_;
        *(bf16x4*)&sY[wv][p][16 + c0] = vx_;
        *(bf16x4*)&sY[wv][p][32 + c0] = vy_;

        // ---- prefetch row r+2 into the slot row r-1 just vacated ----
        if (r < ROWS - 1) {
            prefetch_row(i0 + r + 2, r % 3);
            ru_n = ru[(size_t)b * plane + (size_t)(i0 + r + 1) * WW + j0 + p];
        }

        // ---- GEMM1: h = relu(W0_aug . Y^T) ----
        const bf16x8 yb0 = *(const bf16x8*)&sY[wv][p][8 * q];
        const bf16x8 yb1 = *(const bf16x8*)&sY[wv][p][32 + 8 * q];
        f32x4 acc[8];
        #pragma unroll
        for (int t = 0; t < 8; ++t) {
            acc[t] = f32x4{0.f, 0.f, 0.f, 0.f};
            acc[t] = mfma16(a0[t], yb0, acc[t]);
            acc[t] = mfma16(a1[t], yb1, acc[t]);
        }
        #pragma unroll
        for (int t = 0; t < 8; ++t) {
            bf16x4 hv;
            #pragma unroll
            for (int r2 = 0; r2 < 4; ++r2)
                hv[r2] = (__bf16)fmaxf(acc[t][r2], 0.f);
            *(bf16x4*)&sH[wv][p][16 * t + 4 * q] = hv;   // D: col=px=p, row=4q+r2
        }
        // same-wave LDS write->read: lgkmcnt-ordered, no barrier
        f32x4 u = f32x4{0.f, 0.f, 0.f, 0.f};
        #pragma unroll
        for (int s2 = 0; s2 < 4; ++s2) {
            const bf16x8 hb = *(const bf16x8*)&sH[wv][p][32 * s2 + 8 * q];
            u = mfma16(aw1[s2], hb, u);
        }

        // ---- epilogue: out[c][i][j0+p] = x + u*mask, c = 4q+r2 (exact fp32 x) ----
        const int ig = i0 + r;
        const float m = (ru_c > 0.5f) ? 1.f : 0.f;
        float* ob = out + (size_t)b * CH * plane + (size_t)ig * WW + j0 + p;
        #pragma unroll
        for (int r2 = 0; r2 < 4; ++r2) {
            const int c = 4 * q + r2;
            ob[(size_t)c * plane] = fmaf(u[r2], m, sX[wv][s0][c][ix]);
        }
        ru_c = ru_n;
    }
}

extern "C" void kernel_launch(void* const* d_in, const int* in_sizes, int n_in,
                              void* d_out, int out_size, void* d_ws, size_t ws_size,
                              hipStream_t stream) {
    const float* x  = (const float*)d_in[0];
    const float* w0 = (const float*)d_in[1];
    const float* b0 = (const float*)d_in[2];
    const float* w1 = (const float*)d_in[3];
    const float* ru = (const float*)d_in[4];
    float* out = (float*)d_out;

    dim3 grid(2048);   // 8192 wave-tiles / 4 waves per block
    dim3 block(256);
    hipLaunchKernelGGL(ca_wave, grid, block, 0, stream, x, w0, b0, w1, ru, out);
}